// Round 10
// baseline (43.822 us; speedup 1.0000x reference)
//
#include <hip/hip_runtime.h>
#include <hip/hip_bf16.h>
#include <math.h>

// loss = w * mean((sim_o - sim_t)^2);  ||OO^T - TT^T||_F^2 =
//   ||O^T O||^2 + ||T^T T||^2 - 2||O^T T||^2   (diag mask is a no-op).
// 3 launches, no global barriers (R6/R7: any grid barrier ~70us), no heavy
// atomics (R3), no 1-wave latency-bound blocks (R9):
//   K1 transpose: 512 blocks x 32 k-rows (2/CU — R5-proven occupancy)
//   K2 gram: R8-verbatim LDS MFMA core (KS=64, XCD-grouped chunks)
//   K3 reduce: 768 x 64-thread blocks (3/CU); last block finalizes out[0].

#define N_ROWS 8192
#define DDIM   256
#define NC     32                  // K chunks
#define KC     (N_ROWS / NC)       // 256 rows / chunk
#define KS     64                  // k rows staged per iter
#define NITER  (KC / KS)           // 4
#define PART_STRIDE 196608         // ushorts per chunk = 3 grams * 16 tiles * 4096
#define NRED   768

// ws layout: float ws[0] = scalar acc; u32 ctr at ws[4];
// obt (bf16, 2 matrices [f][k]) at OBT_UOFF ushorts; partials after.
#define OBT_UOFF  32
#define MAT_USZ   (DDIM * N_ROWS)            // 2,097,152 ushorts per matrix
#define PART_UOFF (OBT_UOFF + 2 * MAT_USZ)

typedef __bf16 bf16x8 __attribute__((ext_vector_type(8)));
typedef short  short8 __attribute__((ext_vector_type(8)));
typedef unsigned short us4 __attribute__((ext_vector_type(4)));
typedef unsigned short us8 __attribute__((ext_vector_type(8)));
typedef float  f32x16 __attribute__((ext_vector_type(16)));
typedef unsigned int u32;

__device__ inline unsigned short f2bu(float x) {
    __hip_bfloat16 h = __float2bfloat16(x);
    return __builtin_bit_cast(unsigned short, h);
}
__device__ inline float u2f(unsigned short u) {
    unsigned int v = ((unsigned int)u) << 16;
    return __builtin_bit_cast(float, v);
}
__device__ inline void gload_lds16(const void* g, void* l) {
    __builtin_amdgcn_global_load_lds(
        (const __attribute__((address_space(1))) u32*)g,
        (__attribute__((address_space(3))) u32*)l, 16, 0, 0);
}

// ---- K1: normalize + bf16 + transpose -> obt [f][k] ----
// 512 blocks: (b&1) matrix, (b>>1)*32 k-rows. Phase 1: coalesced float4 rows,
// wave norm-reduce, ushort4 into LDS [k][f] (stride 260). Phase 2: 8 x
// ds_read_b64 per thread, in-register 8x4 u16 transpose, 4 x 16B stores
// (64B contiguous per 4 lanes).
__global__ __launch_bounds__(256) void transpose_kernel(const float* __restrict__ O,
                                                        const float* __restrict__ T,
                                                        float* __restrict__ ws) {
    int tid = threadIdx.x;
    if (blockIdx.x == 0 && tid == 0) {
        ws[0] = 0.0f;
        ((u32*)(ws + 4))[0] = 0u;
    }
    int b = blockIdx.x;
    const float* src = (b & 1) ? T : O;
    unsigned short* dst =
        (unsigned short*)ws + OBT_UOFF + (size_t)(b & 1) * MAT_USZ;
    int kb = (b >> 1) * 32;

    __shared__ unsigned short lt[32 * 260];   // [k][f], stride 260 (16.6 KB)
    int w = tid >> 6, l = tid & 63;
    #pragma unroll
    for (int j = 0; j < 8; ++j) {
        int r = j * 4 + w;
        float4 v = *reinterpret_cast<const float4*>(
            src + (size_t)(kb + r) * DDIM + l * 4);
        float ss = v.x * v.x + v.y * v.y + v.z * v.z + v.w * v.w;
        #pragma unroll
        for (int off = 32; off > 0; off >>= 1) ss += __shfl_xor(ss, off);
        float inv = 1.0f / fmaxf(sqrtf(ss), 1e-8f);
        us4 u;
        u[0] = f2bu(v.x * inv); u[1] = f2bu(v.y * inv);
        u[2] = f2bu(v.z * inv); u[3] = f2bu(v.w * inv);
        *reinterpret_cast<us4*>(&lt[r * 260 + l * 4]) = u;
    }
    __syncthreads();
    int ko = tid & 3;          // k-octet 0..3
    int fq = tid >> 2;         // f-quad 0..63
    us4 rr[8];
    #pragma unroll
    for (int j = 0; j < 8; ++j)
        rr[j] = *reinterpret_cast<const us4*>(&lt[(ko * 8 + j) * 260 + fq * 4]);
    #pragma unroll
    for (int i = 0; i < 4; ++i) {
        us8 o;
        #pragma unroll
        for (int j = 0; j < 8; ++j) o[j] = rr[j][i];
        *reinterpret_cast<us8*>(
            &dst[(size_t)(fq * 4 + i) * N_ROWS + kb + ko * 8]) = o;
    }
}

// ---- K2: MFMA gram partials (R8-verbatim core) ----
// 512 blocks; XCD-grouped decode: chunk = (bid&7)*4 + (bid>>7), ti = (bid>>3)&15
// -> a chunk's 16 tile-blocks share one XCD: slab re-reads hit its L2.
// 4 waves (2x2 of 32x32); slabs [f 64][k 64] bf16, k-octets XOR-swizzled by
// (f&7) via pre-swizzled global src (linear LDS dest, as gload_lds requires).
__global__ __launch_bounds__(256) void gram_kernel(float* __restrict__ ws) {
    const unsigned short* obt = (const unsigned short*)ws + OBT_UOFF;
    unsigned short* part = (unsigned short*)ws + PART_UOFF;

    int bid = blockIdx.x;
    int c  = (bid & 7) * 4 + (bid >> 7);          // K-chunk 0..31
    int ti = (bid >> 3) & 15;                     // tile 0..15
    int tm = ti >> 2, tn = ti & 3;
    int tid = threadIdx.x, lane = tid & 63, wid = tid >> 6;
    int wm = wid >> 1, wn = wid & 1;
    int k0 = c * KC;

    __shared__ __align__(16) unsigned short slabs[2][4][64 * KS];   // 64 KiB

    f32x16 acc_oo, acc_tt, acc_ot;
    #pragma unroll
    for (int e = 0; e < 16; ++e) { acc_oo[e] = 0.f; acc_tt[e] = 0.f; acc_ot[e] = 0.f; }

    // wave wid stages slab wid: {0:O_m, 1:O_n, 2:T_m, 3:T_n}
    int sl = wid;
    int mat = sl >> 1;
    int ft = (sl & 1) ? tn : tm;
    int frow = lane >> 3;                         // f-row 0..7 per stage instr
    int swz8 = ((lane & 7) ^ (frow & 7)) * 8;     // XOR: inverse == forward
    const unsigned short* slab_src =
        obt + (size_t)mat * MAT_USZ + (size_t)(ft * 64 + frow) * N_ROWS + swz8;

    auto stage = [&](int buf, int it) {
        int kb = k0 + it * KS;
        unsigned short* ld = &slabs[buf][sl][0];
        #pragma unroll
        for (int i = 0; i < 8; ++i)               // f-rows i*8+frow, 1KB/instr
            gload_lds16(slab_src + kb + (size_t)(i * 8) * N_ROWS, ld + i * 512);
    };

    int fm = wm * 32 + (lane & 31);
    int fn = wn * 32 + (lane & 31);
    int jhalf = lane >> 5;
    auto frag = [&](int buf, int s, int fl, int kk) -> bf16x8 {
        int j0 = kk * 2 + jhalf;                  // k-octet 0..7
        const unsigned short* p = &slabs[buf][s][fl * KS + ((j0 ^ (fl & 7)) * 8)];
        return __builtin_bit_cast(bf16x8, *reinterpret_cast<const short8*>(p));
    };

    stage(0, 0);
    __syncthreads();
    int cur = 0;
    for (int it = 0; it < NITER; ++it) {
        if (it + 1 < NITER) stage(cur ^ 1, it + 1);
        #pragma unroll
        for (int kk = 0; kk < 4; ++kk) {
            bf16x8 ao = frag(cur, 0, fm, kk);
            bf16x8 bo = frag(cur, 1, fn, kk);
            bf16x8 at = frag(cur, 2, fm, kk);
            bf16x8 bt = frag(cur, 3, fn, kk);
            acc_oo = __builtin_amdgcn_mfma_f32_32x32x16_bf16(ao, bo, acc_oo, 0, 0, 0);
            acc_tt = __builtin_amdgcn_mfma_f32_32x32x16_bf16(at, bt, acc_tt, 0, 0, 0);
            acc_ot = __builtin_amdgcn_mfma_f32_32x32x16_bf16(ao, bt, acc_ot, 0, 0, 0);
        }
        __syncthreads();                          // drains vmcnt+lgkm
        cur ^= 1;
    }

    // C/D layout (m74/m101): col=lane&31, row=(reg&3)+8*(reg>>2)+4*(lane>>5)
    unsigned int tb = (unsigned int)(c * 16 + ti) * 3;
    #pragma unroll
    for (int reg = 0; reg < 16; ++reg) {
        int row = (reg & 3) + 8 * (reg >> 2) + ((lane >> 5) << 2);
        int col = lane & 31;
        int idx = (wm * 32 + row) * 64 + (wn * 32 + col);
        part[(size_t)(tb + 0) * 4096 + idx] = f2bu(acc_oo[reg]);
        part[(size_t)(tb + 1) * 4096 + idx] = f2bu(acc_tt[reg]);
        part[(size_t)(tb + 2) * 4096 + idx] = f2bu(acc_ot[reg]);
    }
}

// ---- K3: chunk-sum + Frobenius combine; last block finalizes ----
// 768 x 64-thread blocks (3/CU) — R8's 192x256 left 64 CUs idle.
__global__ __launch_bounds__(64) void reduce_kernel(const float* __restrict__ W,
                                                    float* __restrict__ out,
                                                    float* __restrict__ ws) {
    const unsigned short* part = (const unsigned short*)ws + PART_UOFF;
    u32* ctr = (u32*)(ws + 4);
    int tid = threadIdx.x;
    int gid = blockIdx.x * 64 + tid;              // 49152 threads
    int base = gid * 4;
    float s0 = 0.f, s1 = 0.f, s2 = 0.f, s3 = 0.f;
    for (int cc = 0; cc < NC; ++cc) {
        ushort4 u = *reinterpret_cast<const ushort4*>(
            &part[(size_t)cc * PART_STRIDE + base]);
        s0 += u2f(u.x); s1 += u2f(u.y); s2 += u2f(u.z); s3 += u2f(u.w);
    }
    int g = (base >> 12) % 3;                     // layout: ((c*16+ti)*3+g)*4096+e
    float s = s0 * s0 + s1 * s1 + s2 * s2 + s3 * s3;
    if (g == 2) s = -2.0f * s;
    #pragma unroll
    for (int off = 32; off > 0; off >>= 1) s += __shfl_down(s, off);
    if (tid == 0) {
        atomicAdd(&ws[0], s);
        __threadfence();
        unsigned int r = atomicAdd(&ctr[0], 1u);
        if (r == NRED - 1) {                      // last finishing block
            float v = __hip_atomic_load(&ws[0], __ATOMIC_ACQUIRE,
                                        __HIP_MEMORY_SCOPE_AGENT);
            out[0] = v * W[0] / ((float)N_ROWS * (float)N_ROWS);
        }
    }
}

extern "C" void kernel_launch(void* const* d_in, const int* in_sizes, int n_in,
                              void* d_out, int out_size, void* d_ws, size_t ws_size,
                              hipStream_t stream) {
    const float* O = (const float*)d_in[0];
    const float* T = (const float*)d_in[1];
    const float* W = (const float*)d_in[2];
    float* out = (float*)d_out;
    float* ws = (float*)d_ws;

    transpose_kernel<<<512, 256, 0, stream>>>(O, T, ws);
    gram_kernel<<<512, 256, 0, stream>>>(ws);
    reduce_kernel<<<NRED, 64, 0, stream>>>(W, out, ws);
}

// Round 11
// 32.842 us; speedup vs baseline: 1.3343x; 1.3343x over previous
//
#include <hip/hip_runtime.h>
#include <hip/hip_bf16.h>
#include <math.h>

// loss = w * mean((sim_o - sim_t)^2);  ||OO^T - TT^T||_F^2 =
//   ||O^T O||^2 + ||T^T T||^2 - 2||O^T T||^2   (diag mask is a no-op).
// EXACT R5 kernel bodies (best: 31.4us) with ONE change: finalize fused into
// reduce via last-block counter (R8/R10-proven), 4 launches -> 3.
// Lessons pinned: no grid barriers (~70us, R6/R7); no 1-wave no-LDS gram (R9);
// no b64-gather transpose (R9/R10, ~+9us); no fp32 gram atomics (R3).

#define N_ROWS 8192
#define DDIM   256
#define NC     32                  // K chunks
#define KC     (N_ROWS / NC)       // 256 rows / chunk
#define KS     64                  // k rows staged per iter
#define NITER  (KC / KS)           // 4
#define PART_STRIDE 196608         // ushorts per chunk = 3 grams * 16 tiles * 4096
#define NRED   192

// ws layout: float ws[0] = scalar acc; u32 ctr at ws[4];
// obt (bf16, 2 matrices [f][k]) at OBT_UOFF ushorts; partials after.
#define OBT_UOFF  32
#define MAT_USZ   (DDIM * N_ROWS)            // 2,097,152 ushorts per matrix
#define PART_UOFF (OBT_UOFF + 2 * MAT_USZ)

typedef __bf16 bf16x8 __attribute__((ext_vector_type(8)));
typedef short  short8 __attribute__((ext_vector_type(8)));
typedef unsigned short ushort8 __attribute__((ext_vector_type(8)));
typedef float  f32x16 __attribute__((ext_vector_type(16)));
typedef unsigned int u32;

__device__ inline unsigned short f2bu(float x) {
    __hip_bfloat16 h = __float2bfloat16(x);
    return __builtin_bit_cast(unsigned short, h);
}
__device__ inline float u2f(unsigned short u) {
    unsigned int v = ((unsigned int)u) << 16;
    return __builtin_bit_cast(float, v);
}
__device__ inline void gload_lds16(const void* g, void* l) {
    __builtin_amdgcn_global_load_lds(
        (const __attribute__((address_space(1))) u32*)g,
        (__attribute__((address_space(3))) u32*)l, 16, 0, 0);
}

// ---- K1: normalize + bf16 + transpose (R5-exact) ----
// 512 blocks: (b&1) matrix, (b>>1)*32 k-rows. Wave per row-load (coalesced
// 1KB/row); LDS-staged transpose; thread f writes its 32 k contiguous.
__global__ __launch_bounds__(256) void transpose_kernel(const float* __restrict__ O,
                                                        const float* __restrict__ T,
                                                        float* __restrict__ ws) {
    int tid = threadIdx.x;
    if (blockIdx.x == 0 && tid == 0) {
        ws[0] = 0.0f;
        ((u32*)(ws + 4))[0] = 0u;
    }
    int b = blockIdx.x;
    const float* src = (b & 1) ? T : O;
    unsigned short* dst =
        (unsigned short*)ws + OBT_UOFF + (size_t)(b & 1) * MAT_USZ;
    int kb = (b >> 1) * 32;
    __shared__ unsigned short lt[32][260];   // +pad to spread banks
    int w = tid >> 6, l = tid & 63;
    #pragma unroll
    for (int j = 0; j < 8; ++j) {
        int r = j * 4 + w;
        float4 v = *reinterpret_cast<const float4*>(
            src + (size_t)(kb + r) * DDIM + l * 4);
        float ss = v.x * v.x + v.y * v.y + v.z * v.z + v.w * v.w;
        #pragma unroll
        for (int off = 32; off > 0; off >>= 1) ss += __shfl_xor(ss, off);
        float inv = 1.0f / fmaxf(sqrtf(ss), 1e-8f);
        ushort4 u;
        u.x = f2bu(v.x * inv); u.y = f2bu(v.y * inv);
        u.z = f2bu(v.z * inv); u.w = f2bu(v.w * inv);
        *reinterpret_cast<ushort4*>(&lt[r][l * 4]) = u;
    }
    __syncthreads();
    int f = tid;
    #pragma unroll
    for (int s = 0; s < 8; ++s) {
        ushort4 u;
        u.x = lt[s * 4 + 0][f]; u.y = lt[s * 4 + 1][f];
        u.z = lt[s * 4 + 2][f]; u.w = lt[s * 4 + 3][f];
        *reinterpret_cast<ushort4*>(&dst[(size_t)f * N_ROWS + kb + s * 4]) = u;
    }
}

// ---- K2: MFMA gram partials (R5-exact) ----
// grid 512 = 16 tiles (4x4 of 64x64) x 32 K-chunks; 4 waves (2x2 of 32x32).
// LDS slabs [f_local 64][k 64] bf16, k-octets XOR-swizzled by (f&7);
// swizzle applied by permuting the per-lane GLOBAL src (LDS dest linear,
// as global_load_lds requires). Fragment = one ds_read_b128.
__global__ __launch_bounds__(256) void gram_kernel(float* __restrict__ ws) {
    const unsigned short* obt = (const unsigned short*)ws + OBT_UOFF;
    unsigned short* part = (unsigned short*)ws + PART_UOFF;

    int bid = blockIdx.x;
    int ti = bid & 15, c = bid >> 4;
    int tm = ti >> 2, tn = ti & 3;
    int tid = threadIdx.x, lane = tid & 63, wid = tid >> 6;
    int wm = wid >> 1, wn = wid & 1;
    int k0 = c * KC;

    __shared__ __align__(16) unsigned short slabs[2][4][64 * KS];   // 64 KiB

    f32x16 acc_oo, acc_tt, acc_ot;
    #pragma unroll
    for (int e = 0; e < 16; ++e) { acc_oo[e] = 0.f; acc_tt[e] = 0.f; acc_ot[e] = 0.f; }

    // wave wid stages slab wid: {0:O_m, 1:O_n, 2:T_m, 3:T_n}
    int sl = wid;
    int mat = sl >> 1;
    int ft = (sl & 1) ? tn : tm;
    int frow = lane >> 3;                         // f-row 0..7 per stage instr
    int swz8 = ((lane & 7) ^ (frow & 7)) * 8;     // XOR: inverse == forward
    const unsigned short* slab_src =
        obt + (size_t)mat * MAT_USZ + (size_t)(ft * 64 + frow) * N_ROWS + swz8;

    auto stage = [&](int buf, int it) {
        int kb = k0 + it * KS;
        unsigned short* ld = &slabs[buf][sl][0];
        #pragma unroll
        for (int i = 0; i < 8; ++i)               // f-rows i*8+frow, 1KB/instr
            gload_lds16(slab_src + kb + (size_t)(i * 8) * N_ROWS, ld + i * 512);
    };

    int fm = wm * 32 + (lane & 31);
    int fn = wn * 32 + (lane & 31);
    int jhalf = lane >> 5;
    auto frag = [&](int buf, int s, int fl, int kk) -> bf16x8 {
        int j0 = kk * 2 + jhalf;                  // k-octet 0..7
        const unsigned short* p = &slabs[buf][s][fl * KS + ((j0 ^ (fl & 7)) * 8)];
        return __builtin_bit_cast(bf16x8, *reinterpret_cast<const short8*>(p));
    };

    stage(0, 0);
    __syncthreads();
    int cur = 0;
    for (int it = 0; it < NITER; ++it) {
        if (it + 1 < NITER) stage(cur ^ 1, it + 1);
        #pragma unroll
        for (int kk = 0; kk < 4; ++kk) {
            bf16x8 ao = frag(cur, 0, fm, kk);
            bf16x8 bo = frag(cur, 1, fn, kk);
            bf16x8 at = frag(cur, 2, fm, kk);
            bf16x8 bt = frag(cur, 3, fn, kk);
            acc_oo = __builtin_amdgcn_mfma_f32_32x32x16_bf16(ao, bo, acc_oo, 0, 0, 0);
            acc_tt = __builtin_amdgcn_mfma_f32_32x32x16_bf16(at, bt, acc_tt, 0, 0, 0);
            acc_ot = __builtin_amdgcn_mfma_f32_32x32x16_bf16(ao, bt, acc_ot, 0, 0, 0);
        }
        __syncthreads();                          // drains vmcnt+lgkm
        cur ^= 1;
    }

    // C/D layout (m74/m101): col=lane&31, row=(reg&3)+8*(reg>>2)+4*(lane>>5)
    unsigned int tb = (unsigned int)(c * 16 + ti) * 3;
    #pragma unroll
    for (int reg = 0; reg < 16; ++reg) {
        int row = (reg & 3) + 8 * (reg >> 2) + ((lane >> 5) << 2);
        int col = lane & 31;
        int idx = (wm * 32 + row) * 64 + (wn * 32 + col);
        part[(size_t)(tb + 0) * 4096 + idx] = f2bu(acc_oo[reg]);
        part[(size_t)(tb + 1) * 4096 + idx] = f2bu(acc_tt[reg]);
        part[(size_t)(tb + 2) * 4096 + idx] = f2bu(acc_ot[reg]);
    }
}

// ---- K3: chunk-sum + Frobenius combine (R5-exact) + fused last-block finalize ----
__global__ __launch_bounds__(256) void reduce_kernel(const float* __restrict__ W,
                                                     float* __restrict__ out,
                                                     float* __restrict__ ws) {
    const unsigned short* part = (const unsigned short*)ws + PART_UOFF;
    u32* ctr = (u32*)(ws + 4);
    int tid = threadIdx.x;
    int gid = blockIdx.x * 256 + tid;             // 49152 threads
    int base = gid * 4;
    float s0 = 0.f, s1 = 0.f, s2 = 0.f, s3 = 0.f;
    for (int cc = 0; cc < NC; ++cc) {
        ushort4 u = *reinterpret_cast<const ushort4*>(
            &part[(size_t)cc * PART_STRIDE + base]);
        s0 += u2f(u.x); s1 += u2f(u.y); s2 += u2f(u.z); s3 += u2f(u.w);
    }
    int g = (base >> 12) % 3;                     // layout: ((c*16+ti)*3+g)*4096+e
    float s = s0 * s0 + s1 * s1 + s2 * s2 + s3 * s3;
    if (g == 2) s = -2.0f * s;
    #pragma unroll
    for (int off = 32; off > 0; off >>= 1) s += __shfl_down(s, off);
    __shared__ float wsum[4];
    int l = tid & 63, w = tid >> 6;
    if (l == 0) wsum[w] = s;
    __syncthreads();
    if (tid == 0) {
        atomicAdd(&ws[0], wsum[0] + wsum[1] + wsum[2] + wsum[3]);
        __threadfence();
        unsigned int r = atomicAdd(&ctr[0], 1u);
        if (r == NRED - 1) {                      // last finishing block
            float v = __hip_atomic_load(&ws[0], __ATOMIC_ACQUIRE,
                                        __HIP_MEMORY_SCOPE_AGENT);
            out[0] = v * W[0] / ((float)N_ROWS * (float)N_ROWS);
        }
    }
}

extern "C" void kernel_launch(void* const* d_in, const int* in_sizes, int n_in,
                              void* d_out, int out_size, void* d_ws, size_t ws_size,
                              hipStream_t stream) {
    const float* O = (const float*)d_in[0];
    const float* T = (const float*)d_in[1];
    const float* W = (const float*)d_in[2];
    float* out = (float*)d_out;
    float* ws = (float*)d_ws;

    transpose_kernel<<<512, 256, 0, stream>>>(O, T, ws);
    gram_kernel<<<512, 256, 0, stream>>>(ws);
    reduce_kernel<<<NRED, 256, 0, stream>>>(W, out, ws);
}